// Round 3
// baseline (263.232 us; speedup 1.0000x reference)
//
#include <hip/hip_runtime.h>
#include <math.h>

// Problem constants (from reference setup_inputs)
#define B_    8
#define H_    32
#define D_    128
#define SMAX_ 4096
#define HD_   (H_ * D_)      // 4096 floats = 16 KB per position (contiguous across heads)
#define SCALE 0.5f
#define PSTRIDE (D_ + 2)     // partial record per (split, head): m, l, acc[128]

// ---------------------------------------------------------------------------
// Kernel 1: flash-decode partials.
// grid = B * nsplit blocks (b = blk % 8 -> consecutive blocks hit different
// batch regions), 256 threads. STRIDED split->position map: split s handles
// positions p = s, s+nsplit, s+2*nsplit, ... p <= sl. Every split gets
// ceil(total/nsplit) +-1 positions -> perfectly balanced for any seqlen.
// Per position the block reads k[b,p,:,:] = 16 KB fully contiguous:
//   thread t owns head t>>3, d-slice (t&7)*16.
// Dot reduced over 8-lane clusters; online softmax replicated in cluster.
// ---------------------------------------------------------------------------
__global__ __launch_bounds__(256, 2)
void attn_partial(const float* __restrict__ q,
                  const float* __restrict__ knew,
                  const float* __restrict__ vnew,
                  const float* __restrict__ kcache,
                  const float* __restrict__ vcache,
                  const int* __restrict__ seqlen,
                  float* __restrict__ ws,
                  int nsplit)
{
    const int blk   = blockIdx.x;
    const int b     = blk & (B_ - 1);
    const int split = blk / B_;
    const int tid   = threadIdx.x;
    const int h     = tid >> 3;
    const int ds    = (tid & 7) * 16;
    const int sl    = seqlen[b];

    // q fragment: 16 floats
    float qf[16];
    {
        const float* qp = q + (b * H_ + h) * D_ + ds;
        float4 t0 = *(const float4*)(qp);
        float4 t1 = *(const float4*)(qp + 4);
        float4 t2 = *(const float4*)(qp + 8);
        float4 t3 = *(const float4*)(qp + 12);
        qf[0]=t0.x;  qf[1]=t0.y;  qf[2]=t0.z;  qf[3]=t0.w;
        qf[4]=t1.x;  qf[5]=t1.y;  qf[6]=t1.z;  qf[7]=t1.w;
        qf[8]=t2.x;  qf[9]=t2.y;  qf[10]=t2.z; qf[11]=t2.w;
        qf[12]=t3.x; qf[13]=t3.y; qf[14]=t3.z; qf[15]=t3.w;
    }

    float m = -1e30f, l = 0.f;                 // -1e30 sentinel, NOT -inf (NaN on merge)
    float acc[16];
    #pragma unroll
    for (int j = 0; j < 16; ++j) acc[j] = 0.f;

    const size_t pstep = (size_t)HD_ * nsplit; // bytes between this split's positions
    const float* kp = kcache + (size_t)b * SMAX_ * HD_ + (size_t)split * HD_ + tid * 16;
    const float* vp = vcache + (size_t)b * SMAX_ * HD_ + (size_t)split * HD_ + tid * 16;

// one position from pointers KP/VP (16 floats each, this thread's slice)
#define STEP1(KP, VP) do {                                                    \
    float4 k0 = *(const float4*)(KP);                                         \
    float4 k1 = *(const float4*)((KP)+4);                                     \
    float4 k2 = *(const float4*)((KP)+8);                                     \
    float4 k3 = *(const float4*)((KP)+12);                                    \
    float4 v0 = *(const float4*)(VP);                                         \
    float4 v1 = *(const float4*)((VP)+4);                                     \
    float4 v2 = *(const float4*)((VP)+8);                                     \
    float4 v3 = *(const float4*)((VP)+12);                                    \
    float s = qf[0]*k0.x+qf[1]*k0.y+qf[2]*k0.z+qf[3]*k0.w                     \
            + qf[4]*k1.x+qf[5]*k1.y+qf[6]*k1.z+qf[7]*k1.w                     \
            + qf[8]*k2.x+qf[9]*k2.y+qf[10]*k2.z+qf[11]*k2.w                   \
            + qf[12]*k3.x+qf[13]*k3.y+qf[14]*k3.z+qf[15]*k3.w;                \
    s += __shfl_xor(s, 1); s += __shfl_xor(s, 2); s += __shfl_xor(s, 4);      \
    s *= SCALE;                                                               \
    float mn = fmaxf(m, s);                                                   \
    float sc = __expf(m - mn);                                                \
    float pr = __expf(s - mn);                                                \
    m = mn; l = l * sc + pr;                                                  \
    acc[0]=fmaf(pr,v0.x,acc[0]*sc);  acc[1]=fmaf(pr,v0.y,acc[1]*sc);          \
    acc[2]=fmaf(pr,v0.z,acc[2]*sc);  acc[3]=fmaf(pr,v0.w,acc[3]*sc);          \
    acc[4]=fmaf(pr,v1.x,acc[4]*sc);  acc[5]=fmaf(pr,v1.y,acc[5]*sc);          \
    acc[6]=fmaf(pr,v1.z,acc[6]*sc);  acc[7]=fmaf(pr,v1.w,acc[7]*sc);          \
    acc[8]=fmaf(pr,v2.x,acc[8]*sc);  acc[9]=fmaf(pr,v2.y,acc[9]*sc);          \
    acc[10]=fmaf(pr,v2.z,acc[10]*sc);acc[11]=fmaf(pr,v2.w,acc[11]*sc);        \
    acc[12]=fmaf(pr,v3.x,acc[12]*sc);acc[13]=fmaf(pr,v3.y,acc[13]*sc);        \
    acc[14]=fmaf(pr,v3.z,acc[14]*sc);acc[15]=fmaf(pr,v3.w,acc[15]*sc);        \
} while (0)

    int p = split;
    // unroll-2: positions p and p+nsplit, 16 float4 loads in flight
    for (; p + nsplit < sl; p += 2 * nsplit) {
        const float* kp1 = kp + pstep;
        const float* vp1 = vp + pstep;
        float4 a0 = *(const float4*)(kp);
        float4 a1 = *(const float4*)(kp+4);
        float4 a2 = *(const float4*)(kp+8);
        float4 a3 = *(const float4*)(kp+12);
        float4 b0 = *(const float4*)(kp1);
        float4 b1 = *(const float4*)(kp1+4);
        float4 b2 = *(const float4*)(kp1+8);
        float4 b3 = *(const float4*)(kp1+12);
        float4 u0 = *(const float4*)(vp);
        float4 u1 = *(const float4*)(vp+4);
        float4 u2 = *(const float4*)(vp+8);
        float4 u3 = *(const float4*)(vp+12);
        float4 w0 = *(const float4*)(vp1);
        float4 w1 = *(const float4*)(vp1+4);
        float4 w2 = *(const float4*)(vp1+8);
        float4 w3 = *(const float4*)(vp1+12);

        float s0 = qf[0]*a0.x+qf[1]*a0.y+qf[2]*a0.z+qf[3]*a0.w
                 + qf[4]*a1.x+qf[5]*a1.y+qf[6]*a1.z+qf[7]*a1.w
                 + qf[8]*a2.x+qf[9]*a2.y+qf[10]*a2.z+qf[11]*a2.w
                 + qf[12]*a3.x+qf[13]*a3.y+qf[14]*a3.z+qf[15]*a3.w;
        float s1 = qf[0]*b0.x+qf[1]*b0.y+qf[2]*b0.z+qf[3]*b0.w
                 + qf[4]*b1.x+qf[5]*b1.y+qf[6]*b1.z+qf[7]*b1.w
                 + qf[8]*b2.x+qf[9]*b2.y+qf[10]*b2.z+qf[11]*b2.w
                 + qf[12]*b3.x+qf[13]*b3.y+qf[14]*b3.z+qf[15]*b3.w;
        s0 += __shfl_xor(s0, 1); s0 += __shfl_xor(s0, 2); s0 += __shfl_xor(s0, 4);
        s1 += __shfl_xor(s1, 1); s1 += __shfl_xor(s1, 2); s1 += __shfl_xor(s1, 4);
        s0 *= SCALE; s1 *= SCALE;

        float mn  = fmaxf(m, fmaxf(s0, s1));
        float sc  = __expf(m - mn);
        float pr0 = __expf(s0 - mn);
        float pr1 = __expf(s1 - mn);
        m = mn;
        l = l * sc + pr0 + pr1;
        acc[0] = fmaf(pr1,w0.x, fmaf(pr0,u0.x, acc[0] *sc));
        acc[1] = fmaf(pr1,w0.y, fmaf(pr0,u0.y, acc[1] *sc));
        acc[2] = fmaf(pr1,w0.z, fmaf(pr0,u0.z, acc[2] *sc));
        acc[3] = fmaf(pr1,w0.w, fmaf(pr0,u0.w, acc[3] *sc));
        acc[4] = fmaf(pr1,w1.x, fmaf(pr0,u1.x, acc[4] *sc));
        acc[5] = fmaf(pr1,w1.y, fmaf(pr0,u1.y, acc[5] *sc));
        acc[6] = fmaf(pr1,w1.z, fmaf(pr0,u1.z, acc[6] *sc));
        acc[7] = fmaf(pr1,w1.w, fmaf(pr0,u1.w, acc[7] *sc));
        acc[8] = fmaf(pr1,w2.x, fmaf(pr0,u2.x, acc[8] *sc));
        acc[9] = fmaf(pr1,w2.y, fmaf(pr0,u2.y, acc[9] *sc));
        acc[10]= fmaf(pr1,w2.z, fmaf(pr0,u2.z, acc[10]*sc));
        acc[11]= fmaf(pr1,w2.w, fmaf(pr0,u2.w, acc[11]*sc));
        acc[12]= fmaf(pr1,w3.x, fmaf(pr0,u3.x, acc[12]*sc));
        acc[13]= fmaf(pr1,w3.y, fmaf(pr0,u3.y, acc[13]*sc));
        acc[14]= fmaf(pr1,w3.z, fmaf(pr0,u3.z, acc[14]*sc));
        acc[15]= fmaf(pr1,w3.w, fmaf(pr0,u3.w, acc[15]*sc));
        kp += 2 * pstep;
        vp += 2 * pstep;
    }
    if (p < sl) {                              // leftover cache position
        STEP1(kp, vp);
        p += nsplit;
    }
    // appended token at position sl lives in knew/vnew; it belongs to this
    // split iff sl % nsplit == split (nsplit is a power of two)
    if ((sl & (nsplit - 1)) == split) {
        const float* kn = knew + (size_t)b * HD_ + tid * 16;
        const float* vn = vnew + (size_t)b * HD_ + tid * 16;
        STEP1(kn, vn);
    }
#undef STEP1

    // write partial record
    float* wsp = ws + (((size_t)b * nsplit + split) * H_ + h) * PSTRIDE;
    if ((tid & 7) == 0) { wsp[0] = m; wsp[1] = l; }
    float* op = wsp + 2 + ds;
    *(float4*)(op)      = make_float4(acc[0],  acc[1],  acc[2],  acc[3]);
    *(float4*)(op + 4)  = make_float4(acc[4],  acc[5],  acc[6],  acc[7]);
    *(float4*)(op + 8)  = make_float4(acc[8],  acc[9],  acc[10], acc[11]);
    *(float4*)(op + 12) = make_float4(acc[12], acc[13], acc[14], acc[15]);
}

// ---------------------------------------------------------------------------
// Kernel 2: combine partials. grid = B*H blocks, 128 threads.
// Phase 1: threads strided over splits -> block max(m), lt = sum(l_s e_s).
// Phase 2: thread t = dim d -> a_d = sum_s e_s * acc[s][d] (coalesced 512B/s).
// ---------------------------------------------------------------------------
__global__ __launch_bounds__(128)
void attn_combine(const float* __restrict__ ws, float* __restrict__ out, int nsplit)
{
    const int bh = blockIdx.x;
    const int b  = bh >> 5;          // / H_
    const int h  = bh & (H_ - 1);
    const int t  = threadIdx.x;

    __shared__ float sm_e[512];      // max nsplit
    __shared__ float sm_w[2];

    const size_t sstride = (size_t)H_ * PSTRIDE;
    const float* base = ws + ((size_t)b * nsplit * H_ + h) * PSTRIDE;

    // phase 1a: max of m over splits
    float mx = -1e30f;
    for (int s = t; s < nsplit; s += 128) mx = fmaxf(mx, base[(size_t)s * sstride]);
    #pragma unroll
    for (int off = 1; off < 64; off <<= 1) mx = fmaxf(mx, __shfl_xor(mx, off));
    if ((t & 63) == 0) sm_w[t >> 6] = mx;
    __syncthreads();
    const float mt = fmaxf(sm_w[0], sm_w[1]);
    __syncthreads();                                   // before sm_w reuse

    // phase 1b: per-split weights e_s and lt
    float le = 0.f;
    for (int s = t; s < nsplit; s += 128) {
        const float* p = base + (size_t)s * sstride;
        float ms = p[0], ls = p[1];
        float e = (ls > 0.f) ? __expf(ms - mt) : 0.f;  // empty split -> weight 0
        sm_e[s] = e;
        le += ls * e;
    }
    #pragma unroll
    for (int off = 1; off < 64; off <<= 1) le += __shfl_xor(le, off);
    if ((t & 63) == 0) sm_w[t >> 6] = le;
    __syncthreads();
    const float lt = sm_w[0] + sm_w[1];

    // phase 2: accumulate dimension t across splits
    const float* ab = base + 2 + t;
    float a = 0.f;
    #pragma unroll 8
    for (int s = 0; s < nsplit; ++s) {
        a += sm_e[s] * ab[(size_t)s * sstride];
    }
    out[bh * D_ + t] = a / lt;
}

extern "C" void kernel_launch(void* const* d_in, const int* in_sizes, int n_in,
                              void* d_out, int out_size, void* d_ws, size_t ws_size,
                              hipStream_t stream) {
    const float* q  = (const float*)d_in[0];
    const float* k  = (const float*)d_in[1];
    const float* v  = (const float*)d_in[2];
    const float* kc = (const float*)d_in[3];
    const float* vc = (const float*)d_in[4];
    const int*   sl = (const int*)d_in[5];
    float* out = (float*)d_out;
    float* ws  = (float*)d_ws;

    // nsplit=256 -> 2048 blocks (8/CU queued), strided position map keeps all
    // blocks busy regardless of seqlen. ws need: 8*256*32*130*4 = ~34 MB.
    int nsplit = 256;
    while (nsplit > 1 &&
           (size_t)B_ * nsplit * H_ * PSTRIDE * sizeof(float) > ws_size) {
        nsplit >>= 1;
    }

    attn_partial<<<B_ * nsplit, 256, 0, stream>>>(q, k, v, kc, vc, sl, ws, nsplit);
    attn_combine<<<B_ * H_, 128, 0, stream>>>(ws, out, nsplit);
}

// Round 4
// 151.510 us; speedup vs baseline: 1.7374x; 1.7374x over previous
//
#include <hip/hip_runtime.h>
#include <math.h>

// Problem constants (from reference setup_inputs)
#define B_    8
#define H_    32
#define D_    128
#define SMAX_ 4096
#define HD_   (H_ * D_)      // 4096 floats = 16 KB per position (contiguous across heads)
#define SCALE 0.5f
#define PSTRIDE (D_ + 2)     // partial record per (split, head): m, l, acc[128]

// ---------------------------------------------------------------------------
// Kernel 1: flash-decode partials.
// grid = B * nsplit blocks (b = blk & 7), 512 threads.
// Thread t owns head t>>4, d-slice (t&15)*8 -> within-position byte offset is
// t*32, so each position's K (and V) read is ONE fully contiguous 16 KB burst.
// STRIDED split->position map: split s handles p = s, s+nsplit, ... p < sl,
// plus the appended token (position sl, from knew/vnew) iff sl%nsplit == s.
// Every split gets ceil(total/nsplit) +-1 positions -> balanced for any sl.
// Dot reduced over 16-lane clusters (shfl_xor 1,2,4,8); online softmax
// replicated within the cluster. Per-thread state kept tiny (~60 VGPR):
// qf[8] + acc[8] + <=32 load regs -> no spills, high occupancy.
// ---------------------------------------------------------------------------
__global__ __launch_bounds__(512, 4)
void attn_partial(const float* __restrict__ q,
                  const float* __restrict__ knew,
                  const float* __restrict__ vnew,
                  const float* __restrict__ kcache,
                  const float* __restrict__ vcache,
                  const int* __restrict__ seqlen,
                  float* __restrict__ ws,
                  int nsplit)
{
    const int blk   = blockIdx.x;
    const int b     = blk & (B_ - 1);
    const int split = blk / B_;
    const int t     = threadIdx.x;
    const int h     = t >> 4;
    const int ds    = (t & 15) * 8;
    const int sl    = seqlen[b];

    float* wsp = ws + (((size_t)b * nsplit + split) * H_ + h) * PSTRIDE;

    // q fragment: 8 floats
    float qf[8];
    {
        const float* qp = q + (b * H_ + h) * D_ + ds;
        float4 t0 = *(const float4*)(qp);
        float4 t1 = *(const float4*)(qp + 4);
        qf[0]=t0.x; qf[1]=t0.y; qf[2]=t0.z; qf[3]=t0.w;
        qf[4]=t1.x; qf[5]=t1.y; qf[6]=t1.z; qf[7]=t1.w;
    }

    float m = -1e30f, l = 0.f;                 // -1e30 sentinel, NOT -inf (NaN on merge)
    float acc[8];
    #pragma unroll
    for (int j = 0; j < 8; ++j) acc[j] = 0.f;

    const size_t pstep = (size_t)HD_ * nsplit;
    const float* kb = kcache + (size_t)b * SMAX_ * HD_ + t * 8;
    const float* vb = vcache + (size_t)b * SMAX_ * HD_ + t * 8;

// one position from pointers KP/VP (8 floats, this thread's slice)
#define STEP1(KP, VP) do {                                                    \
    float4 k0 = *(const float4*)(KP);                                         \
    float4 k1 = *(const float4*)((KP)+4);                                     \
    float4 v0 = *(const float4*)(VP);                                         \
    float4 v1 = *(const float4*)((VP)+4);                                     \
    float s = qf[0]*k0.x+qf[1]*k0.y+qf[2]*k0.z+qf[3]*k0.w                     \
            + qf[4]*k1.x+qf[5]*k1.y+qf[6]*k1.z+qf[7]*k1.w;                    \
    s += __shfl_xor(s, 1); s += __shfl_xor(s, 2);                             \
    s += __shfl_xor(s, 4); s += __shfl_xor(s, 8);                             \
    s *= SCALE;                                                               \
    float mn = fmaxf(m, s);                                                   \
    float sc = __expf(m - mn);                                                \
    float pr = __expf(s - mn);                                                \
    m = mn; l = l * sc + pr;                                                  \
    acc[0]=fmaf(pr,v0.x,acc[0]*sc); acc[1]=fmaf(pr,v0.y,acc[1]*sc);           \
    acc[2]=fmaf(pr,v0.z,acc[2]*sc); acc[3]=fmaf(pr,v0.w,acc[3]*sc);           \
    acc[4]=fmaf(pr,v1.x,acc[4]*sc); acc[5]=fmaf(pr,v1.y,acc[5]*sc);           \
    acc[6]=fmaf(pr,v1.z,acc[6]*sc); acc[7]=fmaf(pr,v1.w,acc[7]*sc);           \
} while (0)

    int p = split;
    const float* kp = kb + (size_t)split * HD_;
    const float* vp = vb + (size_t)split * HD_;
    // unroll-2 over this split's positions: 8 float4 loads in flight/thread
    for (; p + nsplit < sl; p += 2 * nsplit) {
        const float* kq = kp + pstep;
        const float* vq = vp + pstep;
        float4 a0 = *(const float4*)(kp);
        float4 a1 = *(const float4*)(kp + 4);
        float4 b0 = *(const float4*)(kq);
        float4 b1 = *(const float4*)(kq + 4);
        float4 u0 = *(const float4*)(vp);
        float4 u1 = *(const float4*)(vp + 4);
        float4 w0 = *(const float4*)(vq);
        float4 w1 = *(const float4*)(vq + 4);

        float s0 = qf[0]*a0.x+qf[1]*a0.y+qf[2]*a0.z+qf[3]*a0.w
                 + qf[4]*a1.x+qf[5]*a1.y+qf[6]*a1.z+qf[7]*a1.w;
        float s1 = qf[0]*b0.x+qf[1]*b0.y+qf[2]*b0.z+qf[3]*b0.w
                 + qf[4]*b1.x+qf[5]*b1.y+qf[6]*b1.z+qf[7]*b1.w;
        s0 += __shfl_xor(s0, 1); s0 += __shfl_xor(s0, 2);
        s0 += __shfl_xor(s0, 4); s0 += __shfl_xor(s0, 8);
        s1 += __shfl_xor(s1, 1); s1 += __shfl_xor(s1, 2);
        s1 += __shfl_xor(s1, 4); s1 += __shfl_xor(s1, 8);
        s0 *= SCALE; s1 *= SCALE;

        float mn  = fmaxf(m, fmaxf(s0, s1));
        float sc  = __expf(m - mn);
        float pr0 = __expf(s0 - mn);
        float pr1 = __expf(s1 - mn);
        m = mn;
        l = l * sc + pr0 + pr1;
        acc[0] = fmaf(pr1,w0.x, fmaf(pr0,u0.x, acc[0]*sc));
        acc[1] = fmaf(pr1,w0.y, fmaf(pr0,u0.y, acc[1]*sc));
        acc[2] = fmaf(pr1,w0.z, fmaf(pr0,u0.z, acc[2]*sc));
        acc[3] = fmaf(pr1,w0.w, fmaf(pr0,u0.w, acc[3]*sc));
        acc[4] = fmaf(pr1,w1.x, fmaf(pr0,u1.x, acc[4]*sc));
        acc[5] = fmaf(pr1,w1.y, fmaf(pr0,u1.y, acc[5]*sc));
        acc[6] = fmaf(pr1,w1.z, fmaf(pr0,u1.z, acc[6]*sc));
        acc[7] = fmaf(pr1,w1.w, fmaf(pr0,u1.w, acc[7]*sc));
        kp += 2 * pstep;
        vp += 2 * pstep;
    }
    if (p < sl) {                              // leftover cache position
        STEP1(kp, vp);
    }
    // appended token at position sl (knew/vnew), owned by split sl % nsplit
    if ((sl & (nsplit - 1)) == split) {
        const float* kn = knew + (size_t)b * HD_ + t * 8;
        const float* vn = vnew + (size_t)b * HD_ + t * 8;
        STEP1(kn, vn);
    }
#undef STEP1

    // write partial record (m,l replicated across the 16-lane cluster)
    if ((t & 15) == 0) { wsp[0] = m; wsp[1] = l; }
    float* op = wsp + 2 + ds;
    *(float4*)(op)     = make_float4(acc[0], acc[1], acc[2], acc[3]);
    *(float4*)(op + 4) = make_float4(acc[4], acc[5], acc[6], acc[7]);
}

// ---------------------------------------------------------------------------
// Kernel 2: combine partials. grid = B*H blocks, 128 threads.
// Phase 1: threads strided over splits -> block max(m), lt = sum(l_s e_s).
// Phase 2: thread t = dim d -> a_d = sum_s e_s * acc[s][d] (coalesced 512B/s).
// ---------------------------------------------------------------------------
__global__ __launch_bounds__(128)
void attn_combine(const float* __restrict__ ws, float* __restrict__ out, int nsplit)
{
    const int bh = blockIdx.x;
    const int b  = bh >> 5;          // / H_
    const int h  = bh & (H_ - 1);
    const int t  = threadIdx.x;

    __shared__ float sm_e[512];      // max nsplit
    __shared__ float sm_w[2];

    const size_t sstride = (size_t)H_ * PSTRIDE;
    const float* base = ws + ((size_t)b * nsplit * H_ + h) * PSTRIDE;

    // phase 1a: max of m over splits
    float mx = -1e30f;
    for (int s = t; s < nsplit; s += 128) mx = fmaxf(mx, base[(size_t)s * sstride]);
    #pragma unroll
    for (int off = 1; off < 64; off <<= 1) mx = fmaxf(mx, __shfl_xor(mx, off));
    if ((t & 63) == 0) sm_w[t >> 6] = mx;
    __syncthreads();
    const float mt = fmaxf(sm_w[0], sm_w[1]);
    __syncthreads();                                   // before sm_w reuse

    // phase 1b: per-split weights e_s and lt
    float le = 0.f;
    for (int s = t; s < nsplit; s += 128) {
        const float* p = base + (size_t)s * sstride;
        float ms = p[0], ls = p[1];
        float e = (ls > 0.f) ? __expf(ms - mt) : 0.f;  // empty split -> weight 0
        sm_e[s] = e;
        le += ls * e;
    }
    #pragma unroll
    for (int off = 1; off < 64; off <<= 1) le += __shfl_xor(le, off);
    if ((t & 63) == 0) sm_w[t >> 6] = le;
    __syncthreads();
    const float lt = sm_w[0] + sm_w[1];

    // phase 2: accumulate dimension t across splits
    const float* ab = base + 2 + t;
    float a = 0.f;
    #pragma unroll 8
    for (int s = 0; s < nsplit; ++s) {
        a += sm_e[s] * ab[(size_t)s * sstride];
    }
    out[bh * D_ + t] = a / lt;
}

extern "C" void kernel_launch(void* const* d_in, const int* in_sizes, int n_in,
                              void* d_out, int out_size, void* d_ws, size_t ws_size,
                              hipStream_t stream) {
    const float* q  = (const float*)d_in[0];
    const float* k  = (const float*)d_in[1];
    const float* v  = (const float*)d_in[2];
    const float* kc = (const float*)d_in[3];
    const float* vc = (const float*)d_in[4];
    const int*   sl = (const int*)d_in[5];
    float* out = (float*)d_out;
    float* ws  = (float*)d_ws;

    // nsplit=128 -> 1024 blocks x 8 waves, strided map keeps all blocks busy
    // and uniform regardless of seqlen. ws need: 8*128*32*130*4 = ~17 MB.
    int nsplit = 128;
    while (nsplit > 1 &&
           (size_t)B_ * nsplit * H_ * PSTRIDE * sizeof(float) > ws_size) {
        nsplit >>= 1;
    }

    attn_partial<<<B_ * nsplit, 512, 0, stream>>>(q, k, v, kc, vc, sl, ws, nsplit);
    attn_combine<<<B_ * H_, 128, 0, stream>>>(ws, out, nsplit);
}